// Round 5
// baseline (192.493 us; speedup 1.0000x reference)
//
#include <hip/hip_runtime.h>
#include <hip/hip_bf16.h>

typedef unsigned short u16;
typedef __attribute__((ext_vector_type(8))) short bf16x8;
typedef __attribute__((ext_vector_type(4))) float f32x4;
typedef __attribute__((ext_vector_type(8))) unsigned short u16x8;
typedef __attribute__((ext_vector_type(4))) unsigned int u32x4;

#define MFMA16(a, b, c) __builtin_amdgcn_mfma_f32_16x16x32_bf16((a), (b), (c), 0, 0, 0)

// LDS XOR swizzle for 128-byte rows: colbyte ^= SWZB(row). Gives uniform
// 8-lanes-per-16B-slot spread for both the permuted-K reads and V reads.
#define SWZB(row) ((((row) & 3) | ((((row) >> 3) & 1) << 2)) << 4)

__device__ __forceinline__ u16 f2b(float f) {
  union { float f; unsigned u; } c; c.f = f;
  unsigned u = c.u;
  u += 0x7FFFu + ((u >> 16) & 1u);   // RNE
  return (u16)(u >> 16);
}

// packed f32x2 -> bf16x2 (RNE), single VALU inst (m214v22-verified win)
__device__ __forceinline__ unsigned cvt_pk_bf16(float a, float b) {
  unsigned r;
  asm("v_cvt_pk_bf16_f32 %0, %1, %2" : "=v"(r) : "v"(a), "v"(b));
  return r;
}

__device__ __forceinline__ void gload_lds16(const u16* g, u16* l) {
  __builtin_amdgcn_global_load_lds(
      (__attribute__((address_space(1))) void*)(g),
      (__attribute__((address_space(3))) void*)(l),
      16, 0, 0);
}

// ---------------- f32 -> bf16 convert (x) ----------------
__global__ __launch_bounds__(256) void convert_f32_bf16(const float* __restrict__ in,
                                                        u16* __restrict__ out) {
  int i = (blockIdx.x * 256 + threadIdx.x) * 8;   // grid sized exactly
  float4 a = *(const float4*)&in[i];
  float4 b = *(const float4*)&in[i + 4];
  u16x8 o;
  o[0] = f2b(a.x); o[1] = f2b(a.y); o[2] = f2b(a.z); o[3] = f2b(a.w);
  o[4] = f2b(b.x); o[5] = f2b(b.y); o[6] = f2b(b.z); o[7] = f2b(b.w);
  *(u16x8*)&out[i] = o;
}

// ---------------- transpose + convert weights: Wt[n][k] = bf16(W[k][n]) ----------------
__global__ __launch_bounds__(256) void transpose_convert_w(
    const float* __restrict__ W0, const float* __restrict__ W1,
    const float* __restrict__ W2, const float* __restrict__ W3,
    u16* __restrict__ Wts) {
  __shared__ float t[32][33];
  int z = blockIdx.z;
  const float* W = (z == 0) ? W0 : (z == 1) ? W1 : (z == 2) ? W2 : W3;
  u16* Wt = Wts + (size_t)z * 1048576;
  int n0 = blockIdx.x * 32, k0 = blockIdx.y * 32;
  int tx = threadIdx.x, ty = threadIdx.y;
#pragma unroll
  for (int i = 0; i < 32; i += 8)
    t[ty + i][tx] = W[(size_t)(k0 + ty + i) * 1024 + n0 + tx];
  __syncthreads();
#pragma unroll
  for (int i = 0; i < 32; i += 8)
    Wt[(size_t)(n0 + ty + i) * 1024 + k0 + tx] = f2b(t[tx][ty + i]);
}

// ---------------- per-(b,h) V transpose: Vt[d][s] = V[s][d] (64 x 2048 per block) -----
__global__ __launch_bounds__(256) void transpose_v(const u16* __restrict__ V,
                                                   u16* __restrict__ Vt) {
  __shared__ u16 t[32][33];
  int bh = blockIdx.z;
  int s0 = blockIdx.x * 32, d0 = blockIdx.y * 32;
  const u16* Vb = V + (size_t)bh * 131072;
  u16* Vtb = Vt + (size_t)bh * 131072;
  int tx = threadIdx.x, ty = threadIdx.y;
#pragma unroll
  for (int i = 0; i < 32; i += 8)
    t[ty + i][tx] = Vb[(s0 + ty + i) * 64 + d0 + tx];
  __syncthreads();
#pragma unroll
  for (int i = 0; i < 32; i += 8)
    Vtb[(d0 + ty + i) * 2048 + s0 + tx] = t[tx][ty + i];
}

// ---------------- bf16 GEMM: out = A(8192x1024) * W(1024x1024) + bias ----------------
// Wt is n-major (transposed). m97 structure: 128x128 tile, BK=32, 4 waves 2x2,
// global_load_lds width 16, 16x16x32 MFMA, 4x4 acc per wave.
// z==0 (Q proj, bf16 out): folds 1/sqrt(DH) * log2(e) — attention softmax
// then runs in exp2 domain (v_exp_f32 IS 2^x, saves the per-exp multiply).
template <bool F32OUT>
__global__ __launch_bounds__(256) void gemm_kernel(
    const u16* __restrict__ A, const u16* __restrict__ Wt0,
    const float* __restrict__ bias0, const float* __restrict__ bias1,
    const float* __restrict__ bias2,
    u16* __restrict__ outB, float* __restrict__ outF) {
  int z = blockIdx.z;
  const u16* Wt = Wt0 + (size_t)z * 1048576;
  const float* bias = (z == 0) ? bias0 : (z == 1) ? bias1 : bias2;
  u16* outb = outB + (size_t)z * 8388608;
  float oscale = (!F32OUT && z == 0) ? 0.125f * 1.44269504088896f : 1.0f;

  __shared__ u16 Alds[128 * 32];
  __shared__ u16 Blds[128 * 32];
  int tid = threadIdx.x;
  int lane = tid & 63, w = tid >> 6;
  int brow = blockIdx.x * 128;
  int bcol = blockIdx.y * 128;
  int wr = (w >> 1) * 64, wc = (w & 1) * 64;
  int r = lane & 15, half = lane >> 4;

  f32x4 acc[4][4] = {};
  int f0 = (w * 2 + 0) * 512 + lane * 8;   // flat bf16 index in the 128x32 tile
  int f1 = (w * 2 + 1) * 512 + lane * 8;
  const u16* Abase = A + (size_t)brow * 1024;
  const u16* Bbase = Wt + (size_t)bcol * 1024;

  for (int k0 = 0; k0 < 1024; k0 += 32) {
    gload_lds16(Abase + (size_t)(f0 >> 5) * 1024 + k0 + (f0 & 31), &Alds[(w * 2 + 0) * 512]);
    gload_lds16(Abase + (size_t)(f1 >> 5) * 1024 + k0 + (f1 & 31), &Alds[(w * 2 + 1) * 512]);
    gload_lds16(Bbase + (size_t)(f0 >> 5) * 1024 + k0 + (f0 & 31), &Blds[(w * 2 + 0) * 512]);
    gload_lds16(Bbase + (size_t)(f1 >> 5) * 1024 + k0 + (f1 & 31), &Blds[(w * 2 + 1) * 512]);
    __syncthreads();
    bf16x8 af[4], bf[4];
#pragma unroll
    for (int m = 0; m < 4; ++m)
      af[m] = *(const bf16x8*)&Alds[(wr + m * 16 + r) * 32 + half * 8];
#pragma unroll
    for (int n = 0; n < 4; ++n)
      bf[n] = *(const bf16x8*)&Blds[(wc + n * 16 + r) * 32 + half * 8];
#pragma unroll
    for (int m = 0; m < 4; ++m)
#pragma unroll
      for (int n = 0; n < 4; ++n)
        acc[m][n] = MFMA16(af[m], bf[n], acc[m][n]);
    __syncthreads();
  }
#pragma unroll
  for (int m = 0; m < 4; ++m) {
    int rowb = brow + wr + m * 16 + half * 4;
#pragma unroll
    for (int n = 0; n < 4; ++n) {
      int col = bcol + wc + n * 16 + r;
      float bv = bias[col];
#pragma unroll
      for (int j = 0; j < 4; ++j) {
        float v = (acc[m][n][j] + bv) * oscale;
        size_t idx = (size_t)(rowb + j) * 1024 + col;
        if (F32OUT) outF[idx] = v;
        else        outb[idx] = f2b(v);
      }
    }
  }
}

// ---------------- causal flash attention per (b,h): N=2048, D=64 ----------------
// Swapped-operand structure: S^T = MFMA(K, Q) in exp2-domain (log2e folded into
// Q). Lane owns one q-row; permuted K rows make the lane's 16 P values exactly
// the PV B-fragment. Softmax lane-local + 2 shuffles; defer-max (THR=8) skips
// the O-rescale on most tiles; P->bf16 via v_cvt_pk_bf16_f32. K/V tiles staged
// into double-buffered XOR-swizzled LDS via async global_load_lds.
__device__ __forceinline__ void attn_stage(
    const u16* __restrict__ Kb, const u16* __restrict__ Vtb,
    u16* Kl, u16* Vl, int kb, int tid) {
  const int row0 = tid >> 3;            // 0..31
  const int cb0 = (tid & 7) << 4;       // byte col within 128B row
  const int row1 = row0 + 32;
  gload_lds16(Kb + (size_t)(kb + row0) * 64 + ((cb0 ^ SWZB(row0)) >> 1), Kl + tid * 8);
  gload_lds16(Kb + (size_t)(kb + row1) * 64 + ((cb0 ^ SWZB(row1)) >> 1), Kl + 2048 + tid * 8);
  gload_lds16(Vtb + (size_t)row0 * 2048 + kb + ((cb0 ^ SWZB(row0)) >> 1), Vl + tid * 8);
  gload_lds16(Vtb + (size_t)row1 * 2048 + kb + ((cb0 ^ SWZB(row1)) >> 1), Vl + 2048 + tid * 8);
}

__device__ __forceinline__ void attn_strip(
    const u16* __restrict__ Qb, const u16* __restrict__ Kb,
    const u16* __restrict__ Vtb, u16* __restrict__ Zb,
    u16 (*Kl)[4096], u16 (*Vl)[4096], int qrow, int nt, int tid) {
  const int lane = tid & 63;
  const int r = lane & 15, half = lane >> 4;
  const bf16x8 qf0 = *(const bf16x8*)&Qb[(qrow + r) * 64 + half * 8];
  const bf16x8 qf1 = *(const bf16x8*)&Qb[(qrow + r) * 64 + 32 + half * 8];
  const int q = qrow + r;
  f32x4 om[4] = {};
  float m_run = -1e30f, l_run = 0.f;

  __syncthreads();                       // seal previous readers of buf0
  attn_stage(Kb, Vtb, Kl[0], Vl[0], 0, tid);
  int cur = 0;

  for (int kt = 0; kt < nt; ++kt) {
    const int kb = kt * 64;
    __syncthreads();                     // drains staging (vmcnt0) + makes visible
    if (kt + 1 < nt) attn_stage(Kb, Vtb, Kl[cur ^ 1], Vl[cur ^ 1], kb + 64, tid);
    const char* Kc = (const char*)Kl[cur];
    const char* Vc = (const char*)Vl[cur];

    f32x4 sT[2][2];
#pragma unroll
    for (int c = 0; c < 2; ++c)
#pragma unroll
      for (int t = 0; t < 2; ++t) {
        const int krow = c * 32 + ((r >> 2) << 3) + t * 4 + (r & 3);
        const char* krp = Kc + krow * 128;
        const bf16x8 kf0 = *(const bf16x8*)(krp + ((half * 16) ^ SWZB(krow)));
        const bf16x8 kf1 = *(const bf16x8*)(krp + ((64 + half * 16) ^ SWZB(krow)));
        f32x4 zacc = {};
        zacc = MFMA16(kf0, qf0, zacc);
        zacc = MFMA16(kf1, qf1, zacc);
        sT[c][t] = zacc;
      }
    if (kt == nt - 1) {   // causal mask, last tile only
#pragma unroll
      for (int c = 0; c < 2; ++c)
#pragma unroll
        for (int t = 0; t < 2; ++t)
#pragma unroll
          for (int j = 0; j < 4; ++j)
            if (kb + c * 32 + half * 8 + t * 4 + j > q) sT[c][t][j] = -1e30f;
    }
    // lane-local tile max (pairwise tree; exp2-domain values)
    float mloc;
    {
      float a0 = fmaxf(fmaxf(sT[0][0][0], sT[0][0][1]), fmaxf(sT[0][0][2], sT[0][0][3]));
      float a1 = fmaxf(fmaxf(sT[0][1][0], sT[0][1][1]), fmaxf(sT[0][1][2], sT[0][1][3]));
      float a2 = fmaxf(fmaxf(sT[1][0][0], sT[1][0][1]), fmaxf(sT[1][0][2], sT[1][0][3]));
      float a3 = fmaxf(fmaxf(sT[1][1][0], sT[1][1][1]), fmaxf(sT[1][1][2], sT[1][1][3]));
      mloc = fmaxf(fmaxf(a0, a1), fmaxf(a2, a3));
    }
    mloc = fmaxf(mloc, __shfl_xor(mloc, 16));
    mloc = fmaxf(mloc, __shfl_xor(mloc, 32));
    // defer-max (T13): rescale only when some lane's max grew past THR=8
    // (P then bounded by 2^8 — bf16/f32 headroom is ample, scaling consistent)
    if (__any(mloc > m_run + 8.0f)) {
      const float nm = fmaxf(m_run, mloc);
      const float corr = __builtin_exp2f(m_run - nm);
      m_run = nm;
      l_run *= corr;
#pragma unroll
      for (int f = 0; f < 4; ++f)
#pragma unroll
        for (int j = 0; j < 4; ++j) om[f][j] *= corr;
    }
    const float mb = m_run;
    float lloc = 0.f;
    u32x4 pw[2];
#pragma unroll
    for (int c = 0; c < 2; ++c)
#pragma unroll
      for (int t = 0; t < 2; ++t) {
        const float e0 = __builtin_exp2f(sT[c][t][0] - mb);
        const float e1 = __builtin_exp2f(sT[c][t][1] - mb);
        const float e2 = __builtin_exp2f(sT[c][t][2] - mb);
        const float e3 = __builtin_exp2f(sT[c][t][3] - mb);
        lloc += (e0 + e1) + (e2 + e3);
        pw[c][t * 2 + 0] = cvt_pk_bf16(e0, e1);
        pw[c][t * 2 + 1] = cvt_pk_bf16(e2, e3);
      }
    lloc += __shfl_xor(lloc, 16);
    lloc += __shfl_xor(lloc, 32);
    l_run += lloc;
    // PV from LDS V fragments
#pragma unroll
    for (int c = 0; c < 2; ++c) {
      const bf16x8 pb = __builtin_bit_cast(bf16x8, pw[c]);
#pragma unroll
      for (int f = 0; f < 4; ++f) {
        const int vrow = f * 16 + r;
        const bf16x8 vf = *(const bf16x8*)(Vc + vrow * 128 + ((c * 64 + half * 16) ^ SWZB(vrow)));
        om[f] = MFMA16(vf, pb, om[f]);
      }
    }
    cur ^= 1;
  }
  const float inv = 1.0f / l_run;
#pragma unroll
  for (int f = 0; f < 4; ++f) {
    ushort4 st;
    st.x = f2b(om[f][0] * inv);
    st.y = f2b(om[f][1] * inv);
    st.z = f2b(om[f][2] * inv);
    st.w = f2b(om[f][3] * inv);
    *(ushort4*)&Zb[(size_t)q * 64 + f * 16 + half * 4] = st;
  }
}

__global__ __launch_bounds__(256) void attn_kernel(
    const u16* __restrict__ Q, const u16* __restrict__ K,
    const u16* __restrict__ Vt, u16* __restrict__ Z) {
  __shared__ u16 Kl[2][4096];
  __shared__ u16 Vl[2][4096];
  // XCD-affinity swizzle: all 16 q-block-pairs of a head land on one XCD
  // (round-robin dispatch: xcd = linear % 8). 8 heads/XCD -> ~4MB L2 set.
  const int L = blockIdx.x;
  const int xcd = L & 7;
  const int i = L >> 3;
  const int bh = ((i >> 4) << 3) + xcd;   // heads with bh%8 == xcd
  const int x = i & 15;                   // q-block pair index
  const int tid = threadIdx.x;
  const int w = tid >> 6;
  const u16* Qb = Q + (size_t)bh * 131072;
  const u16* Kb = K + (size_t)bh * 131072;
  const u16* Vb = Vt + (size_t)bh * 131072;
  u16* Zb = Z + (size_t)bh * 131072;
  attn_strip(Qb, Kb, Vb, Zb, Kl, Vl, x * 64 + w * 16, x + 1, tid);
  attn_strip(Qb, Kb, Vb, Zb, Kl, Vl, (31 - x) * 64 + w * 16, 32 - x, tid);
}

extern "C" void kernel_launch(void* const* d_in, const int* in_sizes, int n_in,
                              void* d_out, int out_size, void* d_ws, size_t ws_size,
                              hipStream_t stream) {
  (void)in_sizes; (void)n_in; (void)out_size; (void)ws_size;
  const float* x  = (const float*)d_in[0];
  const float* Wq = (const float*)d_in[1];
  const float* bq = (const float*)d_in[2];
  const float* Wk = (const float*)d_in[3];
  const float* bk = (const float*)d_in[4];
  const float* Wv = (const float*)d_in[5];
  const float* bv = (const float*)d_in[6];
  const float* Wo = (const float*)d_in[7];
  const float* bo = (const float*)d_in[8];
  float* out = (float*)d_out;

  char* ws = (char*)d_ws;
  u16* xb  = (u16*)(ws);                  // 16 MB, reused as Z after attention
  u16* Wts = (u16*)(ws + 16777216);       // 4 x 2 MB (q,k,v,o; n-major bf16)
  u16* Qb  = (u16*)(ws + 25165824);       // 16 MB
  u16* Kb  = (u16*)(ws + 41943040);       // 16 MB
  u16* Vb  = (u16*)(ws + 58720256);       // 16 MB
  u16* Vtb = (u16*)(ws + 75497472);       // 16 MB  (total 92 MB)

  convert_f32_bf16<<<4096, 256, 0, stream>>>(x, xb);
  {
    dim3 g(32, 32, 4), b(32, 8);
    transpose_convert_w<<<g, b, 0, stream>>>(Wq, Wk, Wv, Wo, Wts);
  }
  {
    dim3 g(64, 8, 3), b(256);
    gemm_kernel<false><<<g, b, 0, stream>>>(xb, Wts, bq, bk, bv, Qb, nullptr);
  }
  {
    dim3 g(64, 2, 64), b(32, 8);
    transpose_v<<<g, b, 0, stream>>>(Vb, Vtb);
  }
  {
    dim3 g(1024), b(256);
    attn_kernel<<<g, b, 0, stream>>>(Qb, Kb, Vtb, xb /* Z */);
  }
  {
    dim3 g(64, 8, 1), b(256);
    gemm_kernel<true><<<g, b, 0, stream>>>(xb, Wts + 3 * 1048576, bo, bo, bo, Qb, out);
  }
}

// Round 6
// 188.853 us; speedup vs baseline: 1.0193x; 1.0193x over previous
//
#include <hip/hip_runtime.h>
#include <hip/hip_bf16.h>

typedef unsigned short u16;
typedef __attribute__((ext_vector_type(8))) short bf16x8;
typedef __attribute__((ext_vector_type(4))) float f32x4;
typedef __attribute__((ext_vector_type(8))) unsigned short u16x8;
typedef __attribute__((ext_vector_type(4))) unsigned int u32x4;

#define MFMA16(a, b, c) __builtin_amdgcn_mfma_f32_16x16x32_bf16((a), (b), (c), 0, 0, 0)

// LDS XOR swizzle for 128-byte rows: colbyte ^= SWZB(row). Gives uniform
// 8-lanes-per-16B-slot spread for both the permuted-K reads and V reads.
#define SWZB(row) ((((row) & 3) | ((((row) >> 3) & 1) << 2)) << 4)

__device__ __forceinline__ u16 f2b(float f) {
  union { float f; unsigned u; } c; c.f = f;
  unsigned u = c.u;
  u += 0x7FFFu + ((u >> 16) & 1u);   // RNE
  return (u16)(u >> 16);
}

// packed f32x2 -> bf16x2 (RNE), single VALU inst
__device__ __forceinline__ unsigned cvt_pk_bf16(float a, float b) {
  unsigned r;
  asm("v_cvt_pk_bf16_f32 %0, %1, %2" : "=v"(r) : "v"(a), "v"(b));
  return r;
}

__device__ __forceinline__ void gload_lds16(const u16* g, u16* l) {
  __builtin_amdgcn_global_load_lds(
      (__attribute__((address_space(1))) void*)(g),
      (__attribute__((address_space(3))) void*)(l),
      16, 0, 0);
}

// ---------------- f32 -> bf16 convert (x) ----------------
__global__ __launch_bounds__(256) void convert_f32_bf16(const float* __restrict__ in,
                                                        u16* __restrict__ out) {
  int i = (blockIdx.x * 256 + threadIdx.x) * 8;   // grid sized exactly
  float4 a = *(const float4*)&in[i];
  float4 b = *(const float4*)&in[i + 4];
  u16x8 o;
  o[0] = f2b(a.x); o[1] = f2b(a.y); o[2] = f2b(a.z); o[3] = f2b(a.w);
  o[4] = f2b(b.x); o[5] = f2b(b.y); o[6] = f2b(b.z); o[7] = f2b(b.w);
  *(u16x8*)&out[i] = o;
}

// ---------------- transpose + convert weights: Wt[n][k] = bf16(W[k][n]) ----------------
__global__ __launch_bounds__(256) void transpose_convert_w(
    const float* __restrict__ W0, const float* __restrict__ W1,
    const float* __restrict__ W2, const float* __restrict__ W3,
    u16* __restrict__ Wts) {
  __shared__ float t[32][33];
  int z = blockIdx.z;
  const float* W = (z == 0) ? W0 : (z == 1) ? W1 : (z == 2) ? W2 : W3;
  u16* Wt = Wts + (size_t)z * 1048576;
  int n0 = blockIdx.x * 32, k0 = blockIdx.y * 32;
  int tx = threadIdx.x, ty = threadIdx.y;
#pragma unroll
  for (int i = 0; i < 32; i += 8)
    t[ty + i][tx] = W[(size_t)(k0 + ty + i) * 1024 + n0 + tx];
  __syncthreads();
#pragma unroll
  for (int i = 0; i < 32; i += 8)
    Wt[(size_t)(n0 + ty + i) * 1024 + k0 + tx] = f2b(t[tx][ty + i]);
}

// ---------------- per-(b,h) V transpose: Vt[d][s] = V[s][d] (64 x 2048 per block) -----
__global__ __launch_bounds__(256) void transpose_v(const u16* __restrict__ V,
                                                   u16* __restrict__ Vt) {
  __shared__ u16 t[32][33];
  int bh = blockIdx.z;
  int s0 = blockIdx.x * 32, d0 = blockIdx.y * 32;
  const u16* Vb = V + (size_t)bh * 131072;
  u16* Vtb = Vt + (size_t)bh * 131072;
  int tx = threadIdx.x, ty = threadIdx.y;
#pragma unroll
  for (int i = 0; i < 32; i += 8)
    t[ty + i][tx] = Vb[(s0 + ty + i) * 64 + d0 + tx];
  __syncthreads();
#pragma unroll
  for (int i = 0; i < 32; i += 8)
    Vtb[(d0 + ty + i) * 2048 + s0 + tx] = t[tx][ty + i];
}

// ---------------- bf16 GEMM: out = A(8192x1024) * W(1024x1024) + bias ----------------
// Wt is n-major (transposed). m97 structure: 128x128 tile, BK=32, 4 waves 2x2,
// global_load_lds width 16, 16x16x32 MFMA, 4x4 acc per wave.
// z==0 (Q proj, bf16 out): folds 1/sqrt(DH) * log2(e) — softmax runs in exp2 domain.
template <bool F32OUT>
__global__ __launch_bounds__(256) void gemm_kernel(
    const u16* __restrict__ A, const u16* __restrict__ Wt0,
    const float* __restrict__ bias0, const float* __restrict__ bias1,
    const float* __restrict__ bias2,
    u16* __restrict__ outB, float* __restrict__ outF) {
  int z = blockIdx.z;
  const u16* Wt = Wt0 + (size_t)z * 1048576;
  const float* bias = (z == 0) ? bias0 : (z == 1) ? bias1 : bias2;
  u16* outb = outB + (size_t)z * 8388608;
  float oscale = (!F32OUT && z == 0) ? 0.125f * 1.44269504088896f : 1.0f;

  __shared__ u16 Alds[128 * 32];
  __shared__ u16 Blds[128 * 32];
  int tid = threadIdx.x;
  int lane = tid & 63, w = tid >> 6;
  int brow = blockIdx.x * 128;
  int bcol = blockIdx.y * 128;
  int wr = (w >> 1) * 64, wc = (w & 1) * 64;
  int r = lane & 15, half = lane >> 4;

  f32x4 acc[4][4] = {};
  int f0 = (w * 2 + 0) * 512 + lane * 8;   // flat bf16 index in the 128x32 tile
  int f1 = (w * 2 + 1) * 512 + lane * 8;
  const u16* Abase = A + (size_t)brow * 1024;
  const u16* Bbase = Wt + (size_t)bcol * 1024;

  for (int k0 = 0; k0 < 1024; k0 += 32) {
    gload_lds16(Abase + (size_t)(f0 >> 5) * 1024 + k0 + (f0 & 31), &Alds[(w * 2 + 0) * 512]);
    gload_lds16(Abase + (size_t)(f1 >> 5) * 1024 + k0 + (f1 & 31), &Alds[(w * 2 + 1) * 512]);
    gload_lds16(Bbase + (size_t)(f0 >> 5) * 1024 + k0 + (f0 & 31), &Blds[(w * 2 + 0) * 512]);
    gload_lds16(Bbase + (size_t)(f1 >> 5) * 1024 + k0 + (f1 & 31), &Blds[(w * 2 + 1) * 512]);
    __syncthreads();
    bf16x8 af[4], bf[4];
#pragma unroll
    for (int m = 0; m < 4; ++m)
      af[m] = *(const bf16x8*)&Alds[(wr + m * 16 + r) * 32 + half * 8];
#pragma unroll
    for (int n = 0; n < 4; ++n)
      bf[n] = *(const bf16x8*)&Blds[(wc + n * 16 + r) * 32 + half * 8];
#pragma unroll
    for (int m = 0; m < 4; ++m)
#pragma unroll
      for (int n = 0; n < 4; ++n)
        acc[m][n] = MFMA16(af[m], bf[n], acc[m][n]);
    __syncthreads();
  }
#pragma unroll
  for (int m = 0; m < 4; ++m) {
    int rowb = brow + wr + m * 16 + half * 4;
#pragma unroll
    for (int n = 0; n < 4; ++n) {
      int col = bcol + wc + n * 16 + r;
      float bv = bias[col];
#pragma unroll
      for (int j = 0; j < 4; ++j) {
        float v = (acc[m][n][j] + bv) * oscale;
        size_t idx = (size_t)(rowb + j) * 1024 + col;
        if (F32OUT) outF[idx] = v;
        else        outb[idx] = f2b(v);
      }
    }
  }
}

// ---------------- causal flash attention per (b,h): N=2048, D=64 ----------------
// Swapped-operand S^T = MFMA(K, Q) in exp2 domain. Lanes {r,r+16,r+32,r+48} own
// the same q-row with DISJOINT k-subsets. Per-tile cross-lane work is ELIMINATED:
// - om is partitioned by d across replicas (no merge needed)
// - l_run kept as per-lane partial, reduced ONCE at strip end
// - exp reference m_run updated only when __any(mloc > m_run+8) triggers
//   (VCC test, no shuffle); full shuffle-reduce + rescale only on that rare path.
// m_run stays replica-uniform by induction. P bounded by 2^8 (bf16-safe).
__device__ __forceinline__ void attn_stage(
    const u16* __restrict__ Kb, const u16* __restrict__ Vtb,
    u16* Kl, u16* Vl, int kb, int tid) {
  const int row0 = tid >> 3;            // 0..31
  const int cb0 = (tid & 7) << 4;       // byte col within 128B row
  const int row1 = row0 + 32;
  gload_lds16(Kb + (size_t)(kb + row0) * 64 + ((cb0 ^ SWZB(row0)) >> 1), Kl + tid * 8);
  gload_lds16(Kb + (size_t)(kb + row1) * 64 + ((cb0 ^ SWZB(row1)) >> 1), Kl + 2048 + tid * 8);
  gload_lds16(Vtb + (size_t)row0 * 2048 + kb + ((cb0 ^ SWZB(row0)) >> 1), Vl + tid * 8);
  gload_lds16(Vtb + (size_t)row1 * 2048 + kb + ((cb0 ^ SWZB(row1)) >> 1), Vl + 2048 + tid * 8);
}

__device__ __forceinline__ void attn_strip(
    const u16* __restrict__ Qb, const u16* __restrict__ Kb,
    const u16* __restrict__ Vtb, u16* __restrict__ Zb,
    u16 (*Kl)[4096], u16 (*Vl)[4096], int qrow, int nt, int tid) {
  const int lane = tid & 63;
  const int r = lane & 15, half = lane >> 4;
  const bf16x8 qf0 = *(const bf16x8*)&Qb[(qrow + r) * 64 + half * 8];
  const bf16x8 qf1 = *(const bf16x8*)&Qb[(qrow + r) * 64 + 32 + half * 8];
  const int q = qrow + r;
  f32x4 om[4] = {};
  float m_run = -1e30f, l_run = 0.f;     // l_run = per-lane PARTIAL sum

  __syncthreads();                       // seal previous readers of buf0
  attn_stage(Kb, Vtb, Kl[0], Vl[0], 0, tid);
  int cur = 0;

  for (int kt = 0; kt < nt; ++kt) {
    const int kb = kt * 64;
    __syncthreads();                     // drains staging (vmcnt0) + makes visible
    if (kt + 1 < nt) attn_stage(Kb, Vtb, Kl[cur ^ 1], Vl[cur ^ 1], kb + 64, tid);
    const char* Kc = (const char*)Kl[cur];
    const char* Vc = (const char*)Vl[cur];

    f32x4 sT[2][2];
#pragma unroll
    for (int c = 0; c < 2; ++c)
#pragma unroll
      for (int t = 0; t < 2; ++t) {
        const int krow = c * 32 + ((r >> 2) << 3) + t * 4 + (r & 3);
        const char* krp = Kc + krow * 128;
        const bf16x8 kf0 = *(const bf16x8*)(krp + ((half * 16) ^ SWZB(krow)));
        const bf16x8 kf1 = *(const bf16x8*)(krp + ((64 + half * 16) ^ SWZB(krow)));
        f32x4 zacc = {};
        zacc = MFMA16(kf0, qf0, zacc);
        zacc = MFMA16(kf1, qf1, zacc);
        sT[c][t] = zacc;
      }
    if (kt == nt - 1) {   // causal mask, last tile only
#pragma unroll
      for (int c = 0; c < 2; ++c)
#pragma unroll
        for (int t = 0; t < 2; ++t)
#pragma unroll
          for (int j = 0; j < 4; ++j)
            if (kb + c * 32 + half * 8 + t * 4 + j > q) sT[c][t][j] = -1e30f;
    }
    // per-lane tile max (no cross-lane ops on the common path)
    float mloc;
    {
      float a0 = fmaxf(fmaxf(sT[0][0][0], sT[0][0][1]), fmaxf(sT[0][0][2], sT[0][0][3]));
      float a1 = fmaxf(fmaxf(sT[0][1][0], sT[0][1][1]), fmaxf(sT[0][1][2], sT[0][1][3]));
      float a2 = fmaxf(fmaxf(sT[1][0][0], sT[1][0][1]), fmaxf(sT[1][0][2], sT[1][0][3]));
      float a3 = fmaxf(fmaxf(sT[1][1][0], sT[1][1][1]), fmaxf(sT[1][1][2], sT[1][1][3]));
      mloc = fmaxf(fmaxf(a0, a1), fmaxf(a2, a3));
    }
    // defer-max: only when some row grew past THR do the shuffle-reduce+rescale
    if (__any(mloc > m_run + 8.0f)) {
      float mrow = fmaxf(mloc, __shfl_xor(mloc, 16));
      mrow = fmaxf(mrow, __shfl_xor(mrow, 32));
      const float nm = fmaxf(m_run, mrow);
      const float corr = __builtin_exp2f(m_run - nm);
      m_run = nm;
      l_run *= corr;
#pragma unroll
      for (int f = 0; f < 4; ++f)
#pragma unroll
        for (int j = 0; j < 4; ++j) om[f][j] *= corr;
    }
    const float mb = m_run;
    float lloc = 0.f;
    u32x4 pw[2];
#pragma unroll
    for (int c = 0; c < 2; ++c)
#pragma unroll
      for (int t = 0; t < 2; ++t) {
        const float e0 = __builtin_exp2f(sT[c][t][0] - mb);
        const float e1 = __builtin_exp2f(sT[c][t][1] - mb);
        const float e2 = __builtin_exp2f(sT[c][t][2] - mb);
        const float e3 = __builtin_exp2f(sT[c][t][3] - mb);
        lloc += (e0 + e1) + (e2 + e3);
        pw[c][t * 2 + 0] = cvt_pk_bf16(e0, e1);
        pw[c][t * 2 + 1] = cvt_pk_bf16(e2, e3);
      }
    l_run += lloc;                       // per-lane partial; no per-tile reduce
    // PV from LDS V fragments
#pragma unroll
    for (int c = 0; c < 2; ++c) {
      const bf16x8 pb = __builtin_bit_cast(bf16x8, pw[c]);
#pragma unroll
      for (int f = 0; f < 4; ++f) {
        const int vrow = f * 16 + r;
        const bf16x8 vf = *(const bf16x8*)(Vc + vrow * 128 + ((c * 64 + half * 16) ^ SWZB(vrow)));
        om[f] = MFMA16(vf, pb, om[f]);
      }
    }
    cur ^= 1;
  }
  // ONE cross-replica sum reduce for the whole strip
  float lt = l_run;
  lt += __shfl_xor(lt, 16);
  lt += __shfl_xor(lt, 32);
  const float inv = 1.0f / lt;
#pragma unroll
  for (int f = 0; f < 4; ++f) {
    ushort4 st;
    st.x = f2b(om[f][0] * inv);
    st.y = f2b(om[f][1] * inv);
    st.z = f2b(om[f][2] * inv);
    st.w = f2b(om[f][3] * inv);
    *(ushort4*)&Zb[(size_t)q * 64 + f * 16 + half * 4] = st;
  }
}

__global__ __launch_bounds__(256) void attn_kernel(
    const u16* __restrict__ Q, const u16* __restrict__ K,
    const u16* __restrict__ Vt, u16* __restrict__ Z) {
  __shared__ u16 Kl[2][4096];
  __shared__ u16 Vl[2][4096];
  // XCD-affinity swizzle: all 16 q-block-pairs of a head land on one XCD
  // (round-robin dispatch: xcd = linear % 8). 8 heads/XCD -> ~4MB L2 set.
  const int L = blockIdx.x;
  const int xcd = L & 7;
  const int i = L >> 3;
  const int bh = ((i >> 4) << 3) + xcd;   // heads with bh%8 == xcd
  const int x = i & 15;                   // q-block pair index
  const int tid = threadIdx.x;
  const int w = tid >> 6;
  const u16* Qb = Q + (size_t)bh * 131072;
  const u16* Kb = K + (size_t)bh * 131072;
  const u16* Vb = Vt + (size_t)bh * 131072;
  u16* Zb = Z + (size_t)bh * 131072;
  attn_strip(Qb, Kb, Vb, Zb, Kl, Vl, x * 64 + w * 16, x + 1, tid);
  attn_strip(Qb, Kb, Vb, Zb, Kl, Vl, (31 - x) * 64 + w * 16, 32 - x, tid);
}

extern "C" void kernel_launch(void* const* d_in, const int* in_sizes, int n_in,
                              void* d_out, int out_size, void* d_ws, size_t ws_size,
                              hipStream_t stream) {
  (void)in_sizes; (void)n_in; (void)out_size; (void)ws_size;
  const float* x  = (const float*)d_in[0];
  const float* Wq = (const float*)d_in[1];
  const float* bq = (const float*)d_in[2];
  const float* Wk = (const float*)d_in[3];
  const float* bk = (const float*)d_in[4];
  const float* Wv = (const float*)d_in[5];
  const float* bv = (const float*)d_in[6];
  const float* Wo = (const float*)d_in[7];
  const float* bo = (const float*)d_in[8];
  float* out = (float*)d_out;

  char* ws = (char*)d_ws;
  u16* xb  = (u16*)(ws);                  // 16 MB, reused as Z after attention
  u16* Wts = (u16*)(ws + 16777216);       // 4 x 2 MB (q,k,v,o; n-major bf16)
  u16* Qb  = (u16*)(ws + 25165824);       // 16 MB
  u16* Kb  = (u16*)(ws + 41943040);       // 16 MB
  u16* Vb  = (u16*)(ws + 58720256);       // 16 MB
  u16* Vtb = (u16*)(ws + 75497472);       // 16 MB  (total 92 MB)

  convert_f32_bf16<<<4096, 256, 0, stream>>>(x, xb);
  {
    dim3 g(32, 32, 4), b(32, 8);
    transpose_convert_w<<<g, b, 0, stream>>>(Wq, Wk, Wv, Wo, Wts);
  }
  {
    dim3 g(64, 8, 3), b(256);
    gemm_kernel<false><<<g, b, 0, stream>>>(xb, Wts, bq, bk, bv, Qb, nullptr);
  }
  {
    dim3 g(64, 2, 64), b(32, 8);
    transpose_v<<<g, b, 0, stream>>>(Vb, Vtb);
  }
  {
    dim3 g(1024), b(256);
    attn_kernel<<<g, b, 0, stream>>>(Qb, Kb, Vtb, xb /* Z */);
  }
  {
    dim3 g(64, 8, 1), b(256);
    gemm_kernel<true><<<g, b, 0, stream>>>(xb, Wts + 3 * 1048576, bo, bo, bo, Qb, out);
  }
}